// Round 10
// baseline (321.911 us; speedup 1.0000x reference)
//
#include <hip/hip_runtime.h>
#include <math.h>

// ViT Vector Quantizer: z [32,1024,32] f32, embedding [8192,32] f32.
// Outputs (concat, read as f32): z_q_out [N*D], loss [1], idx [N] (as floats).
//
// R10: LDS-free MFMA argmin (codebook is L2-resident) + fused epi/rescore.
//   K0 k_prep        : codebook normalize -> en, en_h, bf16 hi/lo B-frag swizzle;
//                      zero tick/loss.
//   K1 k_argmin_mfma : NO LDS, NO barriers (R9: 64KB LDS -> 2 blocks/CU -> 70%
//                      idle). B-fragments read directly from L2 (eswz = 1 MB,
//                      fits per-XCD L2), depth-2 register ping-pong, 4 row-groups
//                      (64 rows/wave) x KSPLIT=8 (1024 codes). 1024 blocks = 4/CU,
//                      4 waves/SIMD. Packed-u32 top-2 (6-bit tile idx, quant step
//                      <=1.5e-5). Per-rowblock ticket: 8th block merges splits,
//                      flags gap < 1e-4 -> idx_ws[row] = -1.
//   K2 k_epi         : fused: block exact-rescores its own flagged rows (coop,
//                      thread-per-code) then gathers en[idx], writes outputs.

#define D 32
#define KCODES 8192
#define KSPLIT 8
#define TILES_PS 64         // tiles per split (1024 codes)
#define MASK6 0xFFFFFFC0u   // keep 26 bits; low 6 = (63 - tile)
#define MARGIN_Q 1.0e-4f    // unflagged => true gap >= 1e-4 - 2*1.5e-5 - 2*2.4e-5 > 0
#define EPS 1e-12f

typedef short bf16x8 __attribute__((ext_vector_type(8)));
typedef unsigned short u16x8 __attribute__((ext_vector_type(8)));
typedef float f32x4 __attribute__((ext_vector_type(4)));

static __device__ __forceinline__ unsigned short f2bf(float x) {  // RNE bf16 bits
  unsigned u = __float_as_uint(x);
  return (unsigned short)((u + 0x7FFFu + ((u >> 16) & 1u)) >> 16);
}
static __device__ __forceinline__ float bf2f(unsigned short s) {
  return __uint_as_float(((unsigned)s) << 16);
}

// MFMA fragment layouts (validated by R5-R9 exact-idx passes):
//   A[m][k]: m = lane&15, k = (lane>>4)*8 + j
//   B[k][n]: n = lane&15, k = (lane>>4)*8 + j
//   C[m][n]: n = lane&15, m = (lane>>4)*4 + reg

__global__ __launch_bounds__(256) void k_prep(const float* __restrict__ emb,
                                              float* __restrict__ en,
                                              float* __restrict__ en_h,
                                              unsigned short* __restrict__ eswz,
                                              float* __restrict__ loss,
                                              int* __restrict__ tick,
                                              int ntick) {
  int v = blockIdx.x * 256 + threadIdx.x;
  if (v == 0) *loss = 0.f;
  if (v < ntick) tick[v] = 0;
  if (v >= KCODES) return;

  float x[D];
  const float4* p = reinterpret_cast<const float4*>(emb + (size_t)v * D);
#pragma unroll
  for (int j = 0; j < D / 4; ++j) {
    float4 q = p[j];
    x[4 * j + 0] = q.x; x[4 * j + 1] = q.y; x[4 * j + 2] = q.z; x[4 * j + 3] = q.w;
  }
  float ss = 0.f;
#pragma unroll
  for (int j = 0; j < D; ++j) ss = fmaf(x[j], x[j], ss);
  float n = fmaxf(sqrtf(ss), EPS);
#pragma unroll
  for (int j = 0; j < D; ++j) x[j] = x[j] / n;   // true division mirrors reference

  float4* o = reinterpret_cast<float4*>(en + (size_t)v * D);
  float s2 = 0.f;
#pragma unroll
  for (int j = 0; j < D / 4; ++j) {
    float4 q = {x[4 * j], x[4 * j + 1], x[4 * j + 2], x[4 * j + 3]};
    s2 = fmaf(q.x, q.x, fmaf(q.y, q.y, fmaf(q.z, q.z, fmaf(q.w, q.w, s2))));
    o[j] = q;
  }
  en_h[v] = 0.5f * s2;

  unsigned short hi[D], lo[D];
#pragma unroll
  for (int j = 0; j < D; ++j) {
    hi[j] = f2bf(x[j]);
    lo[j] = f2bf(x[j] - bf2f(hi[j]));   // x - bf16(x) exact in fp32
  }
  int tl = v >> 4, m = v & 15;          // B-fragment swizzle: tile = 1024 shorts
#pragma unroll
  for (int q = 0; q < 4; ++q) {
    u16x8 hv, lv;
#pragma unroll
    for (int j = 0; j < 8; ++j) { hv[j] = hi[8 * q + j]; lv[j] = lo[8 * q + j]; }
    *(u16x8*)(eswz + (size_t)tl * 1024 + (q * 16 + m) * 8) = hv;
    *(u16x8*)(eswz + (size_t)tl * 1024 + 512 + (q * 16 + m) * 8) = lv;
  }
}

// One tile's worth of work: 4 independent 3-MFMA chains + packed top-2 update.
#define TILECOMP(BH, BL, T)                                                   \
  {                                                                           \
    const unsigned tid6 = (unsigned)(63 - (T));                               \
    _Pragma("unroll") for (int g = 0; g < 4; ++g) {                           \
      f32x4 acc = __builtin_amdgcn_mfma_f32_16x16x32_bf16(zh[g], (BH), initc, 0, 0, 0); \
      acc = __builtin_amdgcn_mfma_f32_16x16x32_bf16(zh[g], (BL), acc, 0, 0, 0);         \
      acc = __builtin_amdgcn_mfma_f32_16x16x32_bf16(zl[g], (BH), acc, 0, 0, 0);         \
      _Pragma("unroll") for (int r = 0; r < 4; ++r) {                         \
        unsigned q = (__float_as_uint(acc[r]) & MASK6) | tid6;                \
        unsigned tm = min(q, p1[g][r]);                                       \
        p1[g][r] = max(q, p1[g][r]);                                          \
        p2[g][r] = max(tm, p2[g][r]);                                         \
      }                                                                       \
    }                                                                         \
  }

// grid (N/256, KSPLIT); block 256 = 4 waves; each wave: 64 rows x 1024 codes.
__global__ __launch_bounds__(256, 4) void k_argmin_mfma(
    const float* __restrict__ z,
    const unsigned short* __restrict__ eswz,
    unsigned long long* __restrict__ mpp,   // [KSPLIT][N] (s1bits<<32 | 8191-k)
    float* __restrict__ g2,                 // [KSPLIT][N] quantized 2nd-best
    int* __restrict__ tick,
    int* __restrict__ idx_ws, int N) {
  __shared__ int s_old;

  const int tid = threadIdx.x;
  const int wid = tid >> 6, lane = tid & 63;
  const int lane15 = lane & 15, quad = lane >> 4;
  const int rb = blockIdx.x;                    // row-block (256 rows)
  const int split = blockIdx.y;                 // K split
  const int rowbase = rb * 256 + wid * 64;      // this wave's 64 rows

  // --- A-fragments for 4 row groups ---
  bf16x8 zh[4], zl[4];
#pragma unroll
  for (int g = 0; g < 4; ++g) {
    const float4* p =
        reinterpret_cast<const float4*>(z + (size_t)(rowbase + g * 16 + lane15) * D);
    float ss = 0.f;
#pragma unroll
    for (int j = 0; j < 8; ++j) {
      float4 q = p[j];
      ss = fmaf(q.x, q.x, fmaf(q.y, q.y, fmaf(q.z, q.z, fmaf(q.w, q.w, ss))));
    }
    float nn = fmaxf(sqrtf(ss), EPS);
    float4 a0 = p[quad * 2], a1 = p[quad * 2 + 1];
    float xs[8] = {a0.x / nn, a0.y / nn, a0.z / nn, a0.w / nn,
                   a1.x / nn, a1.y / nn, a1.z / nn, a1.w / nn};
#pragma unroll
    for (int j = 0; j < 8; ++j) {
      unsigned short h = f2bf(xs[j]);
      zh[g][j] = (short)h;
      zl[g][j] = (short)f2bf(xs[j] - bf2f(h));
    }
  }

  unsigned p1[4][4], p2[4][4];
#pragma unroll
  for (int g = 0; g < 4; ++g)
#pragma unroll
    for (int r = 0; r < 4; ++r) { p1[g][r] = 0u; p2[g][r] = 0u; }
  const f32x4 initc = {1.25f, 1.25f, 1.25f, 1.25f};  // s' = 1.25 + dot > 0

  // --- B-fragment stream straight from L2 (1 MB eswz is L2-resident).
  // tile t of this split: hi at tp + t*1024, lo at +512 (shorts). 16B/lane.
  const unsigned short* tp = eswz + (size_t)(split * TILES_PS) * 1024 + lane * 8;

  bf16x8 Ah = *(const bf16x8*)(tp);
  bf16x8 Al = *(const bf16x8*)(tp + 512);
  for (int t = 0; t < TILES_PS; t += 2) {
    bf16x8 Bh = *(const bf16x8*)(tp + (t + 1) * 1024);
    bf16x8 Bl = *(const bf16x8*)(tp + (t + 1) * 1024 + 512);
    TILECOMP(Ah, Al, t);
    // t=62 overreads tiles 64,65 of this split: lands in next split / g2 (safe).
    Ah = *(const bf16x8*)(tp + (t + 2) * 1024);
    Al = *(const bf16x8*)(tp + (t + 2) * 1024 + 512);
    TILECOMP(Bh, Bl, t + 1);
  }

  // --- cross-lane merge (16 lanes of each quad hold different codes) ---
#pragma unroll
  for (int g = 0; g < 4; ++g) {
#pragma unroll
    for (int r = 0; r < 4; ++r) {
      unsigned pv = p1[g][r];
      unsigned sb = pv & MASK6;
      int tile = 63 - (int)(pv & 63u);
      int kfull = split * 1024 + tile * 16 + lane15;
      float s1f = __uint_as_float(sb);
      float s2f = __uint_as_float(p2[g][r] & MASK6);
      unsigned long long pk =
          ((unsigned long long)sb << 32) | (unsigned)(8191 - kfull);
#pragma unroll
      for (int m = 1; m <= 8; m <<= 1) {
        unsigned long long op = __shfl_xor(pk, m, 64);
        float os1 = __shfl_xor(s1f, m, 64);
        float os2 = __shfl_xor(s2f, m, 64);
        s2f = fmaxf(fmaxf(s2f, os2), fminf(s1f, os1));  // union 2nd-best
        s1f = fmaxf(s1f, os1);
        pk = (op > pk) ? op : pk;                       // max s, tie -> min k
      }
      if (lane15 == 0) {
        int row = rowbase + g * 16 + quad * 4 + r;
        mpp[(size_t)split * N + row] = pk;
        g2[(size_t)split * N + row] = s2f;
      }
    }
  }

  // --- last-arriving split block merges all 8 splits for this row-block ---
  __threadfence();
  __syncthreads();
  if (tid == 0) s_old = atomicAdd(&tick[rb], 1);
  __syncthreads();
  if (s_old == KSPLIT - 1) {
    __threadfence();
    int row = rb * 256 + tid;                 // one row per thread
    unsigned long long kk[KSPLIT];
    unsigned long long B = 0ull;
#pragma unroll
    for (int s = 0; s < KSPLIT; ++s) {
      kk[s] = mpp[(size_t)s * N + row];
      B = (kk[s] > B) ? kk[s] : B;
    }
    float s1g = __uint_as_float((unsigned)(B >> 32));
    float s2g = -3.4e38f;
#pragma unroll
    for (int s = 0; s < KSPLIT; ++s) {
      float c = (kk[s] == B) ? g2[(size_t)s * N + row]
                             : __uint_as_float((unsigned)(kk[s] >> 32));
      s2g = fmaxf(s2g, c);
    }
    int kb = 8191 - (int)(unsigned)(B & 0xFFFFFFFFull);
    idx_ws[row] = (s1g - s2g < MARGIN_Q) ? -1 : kb;   // -1 => exact rescore in epi
  }
}

// Fused epilogue: exact-rescore this block's flagged rows (thread-per-code,
// coalesced, ~1 us per flagged row), then gather + write outputs.
__global__ __launch_bounds__(256) void k_epi(const float* __restrict__ z,
                                             const float* __restrict__ en,
                                             const float* __restrict__ en_h,
                                             const int* __restrict__ idx_ws,
                                             float* __restrict__ out_z,
                                             float* __restrict__ loss,
                                             float* __restrict__ out_idx,
                                             float scale) {
  __shared__ int nflag;
  __shared__ int flist[256];
  __shared__ int fres[256];
  __shared__ unsigned long long wred[4];
  __shared__ float wsum[4];

  const int tid = threadIdx.x;
  const int lane = tid & 63, wid = tid >> 6;
  int row = blockIdx.x * 256 + tid;
  int kb = idx_ws[row];

  if (tid == 0) nflag = 0;
  __syncthreads();
  int myslot = -1;
  if (kb < 0) { myslot = atomicAdd(&nflag, 1); flist[myslot] = row; }
  __syncthreads();
  const int nf = nflag;

  for (int f = 0; f < nf; ++f) {            // uniform trip count -> safe syncs
    int frow = flist[f];
    const float* zr = z + (size_t)frow * D; // uniform -> scalar loads
    float v[D];
    float ss = 0.f;
#pragma unroll
    for (int d = 0; d < D; ++d) v[d] = zr[d];
#pragma unroll
    for (int d = 0; d < D; ++d) ss = fmaf(v[d], v[d], ss);
    float nn = fmaxf(sqrtf(ss), EPS);
#pragma unroll
    for (int d = 0; d < D; ++d) v[d] = v[d] / nn;

    unsigned long long best = 0ull;
    for (int k = tid; k < KCODES; k += 256) {   // coalesced across threads
      const float4* er = reinterpret_cast<const float4*>(en + (size_t)k * D);
      float a = -en_h[k];
#pragma unroll
      for (int jj = 0; jj < 8; ++jj) {          // exact R4 fma order
        float4 e = er[jj];
        a = fmaf(v[4 * jj + 0], e.x, a);
        a = fmaf(v[4 * jj + 1], e.y, a);
        a = fmaf(v[4 * jj + 2], e.z, a);
        a = fmaf(v[4 * jj + 3], e.w, a);
      }
      unsigned o = __float_as_uint(a);
      o = (o & 0x80000000u) ? ~o : (o | 0x80000000u);
      unsigned long long pk = ((unsigned long long)o << 32) | (unsigned)(8191 - k);
      best = (pk > best) ? pk : best;           // max s, tie -> min k
    }
#pragma unroll
    for (int m = 32; m >= 1; m >>= 1) {
      unsigned long long op = __shfl_xor(best, m, 64);
      best = (op > best) ? op : best;
    }
    if (lane == 0) wred[wid] = best;
    __syncthreads();
    if (tid == 0) {
      unsigned long long m01 = (wred[0] > wred[1]) ? wred[0] : wred[1];
      unsigned long long m23 = (wred[2] > wred[3]) ? wred[2] : wred[3];
      unsigned long long M = (m01 > m23) ? m01 : m23;
      fres[f] = 8191 - (int)(unsigned)(M & 0xFFFFFFFFull);
    }
    __syncthreads();
  }
  if (myslot >= 0) kb = fres[myslot];

  out_idx[row] = (float)kb;  // whole out buffer read back as f32

  const float4* p = reinterpret_cast<const float4*>(z + (size_t)row * D);
  float4 q[D / 4];
#pragma unroll
  for (int j = 0; j < D / 4; ++j) q[j] = p[j];
  float ss = 0.f;
#pragma unroll
  for (int j = 0; j < D / 4; ++j)
    ss = fmaf(q[j].x, q[j].x, fmaf(q[j].y, q[j].y, fmaf(q[j].z, q[j].z, fmaf(q[j].w, q[j].w, ss))));
  float n = fmaxf(sqrtf(ss), EPS);

  const float4* ep = reinterpret_cast<const float4*>(en + (size_t)kb * D);
  float4* op = reinterpret_cast<float4*>(out_z + (size_t)row * D);
  float s = 0.f;
#pragma unroll
  for (int j = 0; j < D / 4; ++j) {
    float4 e = ep[j];
    float4 o;
    o.x = q[j].x + (e.x - q[j].x);  // STE forward value, reference op order
    o.y = q[j].y + (e.y - q[j].y);
    o.z = q[j].z + (e.z - q[j].z);
    o.w = q[j].w + (e.w - q[j].w);
    op[j] = o;
    float dx = e.x - q[j].x / n;  float dy = e.y - q[j].y / n;
    float dz = e.z - q[j].z / n;  float dw = e.w - q[j].w / n;
    s = fmaf(dx, dx, fmaf(dy, dy, fmaf(dz, dz, fmaf(dw, dw, s))));
  }

#pragma unroll
  for (int off = 32; off > 0; off >>= 1) s += __shfl_down(s, off, 64);
  if (lane == 0) wsum[wid] = s;
  __syncthreads();
  if (tid == 0) {
    float tt = (wsum[0] + wsum[1]) + (wsum[2] + wsum[3]);
    atomicAdd(loss, tt * scale);
  }
}

extern "C" void kernel_launch(void* const* d_in, const int* in_sizes, int n_in,
                              void* d_out, int out_size, void* d_ws, size_t ws_size,
                              hipStream_t stream) {
  const float* z = (const float*)d_in[0];
  const float* emb = (const float*)d_in[1];
  const int N = in_sizes[0] / D;  // 32768
  const int K = in_sizes[1] / D;  // 8192

  float* out = (float*)d_out;
  float* out_z = out;                        // N*D
  float* loss = out + (size_t)N * D;         // 1
  float* out_idx = out + (size_t)N * D + 1;  // N

  // ws layout (~5.3 MB). NOTE: g2 must directly follow eswz (argmin's benign
  // 4 KB overread on the last split lands there).
  char* w = (char*)d_ws;
  unsigned long long* mpp = (unsigned long long*)w; w += (size_t)KSPLIT * N * 8; // 2 MB
  float* en = (float*)w;                         w += (size_t)K * D * 4;         // 1 MB
  float* en_h = (float*)w;                       w += (size_t)K * 4;             // 32 KB
  unsigned short* eswz = (unsigned short*)w;     w += (size_t)K * D * 2 * 2;     // 1 MB
  float* g2 = (float*)w;                         w += (size_t)KSPLIT * N * 4;    // 1 MB
  int* idx_ws = (int*)w;                         w += (size_t)N * 4;             // 128 KB
  int* tick = (int*)w;                           w += 1024;

  const int nrb = N / 256;   // 128 row-blocks

  k_prep<<<dim3(K / 256), 256, 0, stream>>>(emb, en, en_h, eswz, loss, tick, nrb);

  k_argmin_mfma<<<dim3(nrb, KSPLIT), 256, 0, stream>>>(
      z, eswz, mpp, g2, tick, idx_ws, N);

  k_epi<<<dim3(N / 256), 256, 0, stream>>>(
      z, en, en_h, idx_ws, out_z, loss, out_idx, 1.25f / (float)((size_t)N * D));
}